// Round 9
// baseline (236.196 us; speedup 1.0000x reference)
//
#include <hip/hip_runtime.h>
#include <hip/hip_bf16.h>

// B=8192, A=8, OBS=128, NACT=32, H=256, D=64 ; N = 65536 rows
typedef __attribute__((ext_vector_type(8))) short bf16x8;   // 8 bf16 (4 VGPRs)
typedef __attribute__((ext_vector_type(4))) float f32x4;

#define MFMA(A, B, C) __builtin_amdgcn_mfma_f32_16x16x32_bf16((A), (B), (C), 0, 0, 0)
#define SB() __builtin_amdgcn_sched_barrier(0)

// ---- ws byte offsets: weights pre-split to bf16 hi/lo planes, [out][k] layout ----
// (lo planes written by setup, unread since round 8: hi-only bf16 verified)
#define OFF_TB    0          // f32 [32]   folded t bias
#define OFF_WT_H  128        // bf16 [32][256]  Mt = SCALE*wk^T*wq
#define OFF_WT_L  16512
#define OFF_WHV_H 32896      // bf16 [64][256]  wv1 h-part
#define OFF_WHV_L 65664
#define OFF_WA_H  98432      // bf16 [64][32]   wv1 action-part
#define OFF_WA_L  102528     // end 106624

// ---- LDS (bytes), total 7168 (round-4 geometry: 16-row single-wave WG) ----
#define SM_HV   0        // f32 [16][68]    4352
#define SM_AT   4352     // f32 [16][8]      512
#define SM_SS   4864     // bf16 [16][72]   2304  (stride 72: rows 16B-aligned)
#define SM_TOT  7168

__device__ __forceinline__ unsigned short f2bf(float v) {   // RNE (setup only)
    unsigned u = __builtin_bit_cast(unsigned, v);
    return (unsigned short)((u + 0x7fffu + ((u >> 16) & 1u)) >> 16);
}
__device__ __forceinline__ float bf2f(unsigned short b) {
    return __builtin_bit_cast(float, ((unsigned)b) << 16);
}
__device__ __forceinline__ ushort2 splitf(float v) {        // (hi, lo residual)
    unsigned short h = f2bf(v);
    unsigned short l = f2bf(v - bf2f(h));
    return make_ushort2(h, l);
}

// __hip_bfloat162 -> u32 reinterpret (bit_cast rejects non-trivially-copyable)
__device__ __forceinline__ unsigned as_u32(__hip_bfloat162 v) {
    unsigned u;
    __builtin_memcpy(&u, &v, sizeof(u));
    return u;
}
__device__ __forceinline__ unsigned pk2(float x, float y) {  // v_cvt_pk_bf16_f32
    return as_u32(__float22bfloat162_rn(make_float2(x, y)));
}
// 8 floats -> bf16x8 (RNE), 4 cvt_pk instrs
__device__ __forceinline__ bf16x8 cvt8(float4 a, float4 b) {
    uint4 H;
    H.x = pk2(a.x, a.y);
    H.y = pk2(a.z, a.w);
    H.z = pk2(b.x, b.y);
    H.w = pk2(b.z, b.w);
    return __builtin_bit_cast(bf16x8, H);
}

// ---------------------------------------------------------------------------
// setup: fold Mt = SCALE*wk^T*wq (+bias), split weights into bf16 planes in
// fragment-native [out][k] layout. wk_b dropped (softmax-invariant, diagonal
// masked — verified round 1).
// ---------------------------------------------------------------------------
__global__ __launch_bounds__(256) void k_setup(const float* __restrict__ wq_w,
                                               const float* __restrict__ wq_b,
                                               const float* __restrict__ wk_w,
                                               const float* __restrict__ wv1,
                                               char* __restrict__ ws) {
    int gid = blockIdx.x * 256 + threadIdx.x;
    if (gid < 8192) {                              // Mt[k][c]
        int k = gid >> 8, c = gid & 255;
        float acc = 0.f;
#pragma unroll 8
        for (int d = 0; d < 64; ++d) acc = fmaf(wk_w[d * 32 + k], wq_w[d * 256 + c], acc);
        ushort2 s = splitf(0.125f * acc);
        ((unsigned short*)(ws + OFF_WT_H))[gid] = s.x;
        ((unsigned short*)(ws + OFF_WT_L))[gid] = s.y;
    } else if (gid < 24576) {                      // wv1 h-part [d][c]
        int i = gid - 8192;
        ushort2 s = splitf(wv1[(i >> 8) * 288 + (i & 255)]);
        ((unsigned short*)(ws + OFF_WHV_H))[i] = s.x;
        ((unsigned short*)(ws + OFF_WHV_L))[i] = s.y;
    } else if (gid < 26624) {                      // wv1 action-part [d][k]
        int i = gid - 24576;
        ushort2 s = splitf(wv1[(i >> 5) * 288 + 256 + (i & 31)]);
        ((unsigned short*)(ws + OFF_WA_H))[i] = s.x;
        ((unsigned short*)(ws + OFF_WA_L))[i] = s.y;
    } else if (gid < 26656) {                      // tb
        int k = gid - 26624;
        float b = 0.f;
#pragma unroll 8
        for (int d = 0; d < 64; ++d) b = fmaf(wk_w[d * 32 + k], wq_b[d], b);
        ((float*)(ws + OFF_TB))[k] = 0.125f * b;
    }
}

// ---------------------------------------------------------------------------
// Fused, block = ONE wave = 16 rows (2 batches). Round 9: round-8 math
// (hi-only bf16) + FORCED load batching. Round-8 PMC showed VGPR=52: the
// compiler sank every preload to its use -> ~50 serialized L2 round-trips/wave
// (Little's law: 58 us wave latency). sched_barrier(0) pins batch issue;
// acts convert to bf16 early (32 regs not 64); weight frags batched mt-major
// (8 loads -> 1 wait); phase-B/W2 loads cross-prefetched. ~13 waits/wave.
// ---------------------------------------------------------------------------
__global__ __launch_bounds__(64, 4) void fused(
    const float* __restrict__ o, const float* __restrict__ onx,
    const float* __restrict__ h, const float* __restrict__ act,
    const float* __restrict__ wv1b, const float* __restrict__ wv2,
    const float* __restrict__ wv2b, const char* __restrict__ ws,
    float* __restrict__ out)
{
    __shared__ __align__(16) char sm[SM_TOT];
    float* HV = (float*)(sm + SM_HV);               // [16][68]
    float* AT = (float*)(sm + SM_AT);               // [16][8]
    unsigned short* SS = (unsigned short*)(sm + SM_SS);  // [16][72]

    const int lane = threadIdx.x;          // 0..63
    const int l15  = lane & 15;
    const int quad = lane >> 4;
    const int n0   = blockIdx.x * 16;
    const int myrow = n0 + l15;            // phase-A fragment row of this lane

    const f32x4 zv = {0.f, 0.f, 0.f, 0.f};
    f32x4 acc_hv[4] = {zv, zv, zv, zv};
    f32x4 acc_t[2]  = {zv, zv};

    bf16x8 Bx[8];                          // act chunks as bf16 (32 VGPR)

    // ---- Phase A-x: batch-load 8 chunks, cvt early, mt-major MFMA ----
    {
        float4 xa[8], xb[8];
#pragma unroll
        for (int ch = 0; ch < 8; ++ch) {
            const float* src = (ch < 4)
                ? o   + (size_t)myrow * 128 + ch * 32 + quad * 8
                : onx + (size_t)myrow * 128 + (ch - 4) * 32 + quad * 8;
            xa[ch] = ((const float4*)src)[0];
            xb[ch] = ((const float4*)src)[1];
        }
        SB();                              // pin: all 16 loads issued first
#pragma unroll
        for (int ch = 0; ch < 8; ++ch) Bx[ch] = cvt8(xa[ch], xb[ch]);
    }
#pragma unroll
    for (int mt = 0; mt < 2; ++mt) {
        bf16x8 wf[8];
#pragma unroll
        for (int ch = 0; ch < 8; ++ch)
            wf[ch] = *(const bf16x8*)(ws + OFF_WT_H +
                     (((mt * 16 + l15) * 256) + ch * 32 + quad * 8) * 2);
        SB();                              // one wait per mt, not per ch
#pragma unroll
        for (int ch = 0; ch < 8; ++ch) acc_t[mt] = MFMA(wf[ch], Bx[ch], acc_t[mt]);
    }

    // ---- Phase A-h: same structure, 4 mt ----
    {
        float4 xa[8], xb[8];
#pragma unroll
        for (int ch = 0; ch < 8; ++ch) {
            const float* src = h + (size_t)myrow * 256 + ch * 32 + quad * 8;
            xa[ch] = ((const float4*)src)[0];
            xb[ch] = ((const float4*)src)[1];
        }
        SB();
#pragma unroll
        for (int ch = 0; ch < 8; ++ch) Bx[ch] = cvt8(xa[ch], xb[ch]);
    }
#pragma unroll
    for (int mt = 0; mt < 4; ++mt) {
        bf16x8 wf[8];
#pragma unroll
        for (int ch = 0; ch < 8; ++ch)
            wf[ch] = *(const bf16x8*)(ws + OFF_WHV_H +
                     (((mt * 16 + l15) * 256) + ch * 32 + quad * 8) * 2);
        SB();
#pragma unroll
        for (int ch = 0; ch < 8; ++ch) acc_hv[mt] = MFMA(wf[ch], Bx[ch], acc_hv[mt]);
    }

    // ---- scores act preload (batched; epilogue-A runs under the latency) ----
    const float* arow = act + (size_t)myrow * 256;
    float4 av0[8], av1[8];
#pragma unroll
    for (int j = 0; j < 8; ++j) {
        av0[j] = *(const float4*)(arow + j * 32 + quad * 4);
        av1[j] = *(const float4*)(arow + j * 32 + 16 + quad * 4);
    }
    SB();

    // ---- epilogue A: HV to LDS (col=l15 -> row n, row=quad*4+reg -> d) ----
#pragma unroll
    for (int mt = 0; mt < 4; ++mt) {
        int d0 = mt * 16 + quad * 4;
        float4 b = *(const float4*)&wv1b[d0];
        f32x4 a = acc_hv[mt];
        *(float4*)&HV[l15 * 68 + d0] =
            make_float4(a[0] + b.x, a[1] + b.y, a[2] + b.z, a[3] + b.w);
    }

    // ---- scores + softmax fully in-register ----
    {
        float t8[8];
        const float* tb = (const float*)(ws + OFF_TB);
#pragma unroll
        for (int mt = 0; mt < 2; ++mt) {
            float4 b = *(const float4*)&tb[mt * 16 + quad * 4];
            t8[mt * 4 + 0] = acc_t[mt][0] + b.x;
            t8[mt * 4 + 1] = acc_t[mt][1] + b.y;
            t8[mt * 4 + 2] = acc_t[mt][2] + b.z;
            t8[mt * 4 + 3] = acc_t[mt][3] + b.w;
        }
        float sc[8];
#pragma unroll
        for (int j = 0; j < 8; ++j) {
            float s = 0.f;
            s = fmaf(t8[0], av0[j].x, s);
            s = fmaf(t8[1], av0[j].y, s);
            s = fmaf(t8[2], av0[j].z, s);
            s = fmaf(t8[3], av0[j].w, s);
            s = fmaf(t8[4], av1[j].x, s);
            s = fmaf(t8[5], av1[j].y, s);
            s = fmaf(t8[6], av1[j].z, s);
            s = fmaf(t8[7], av1[j].w, s);
            sc[j] = s;
        }
#pragma unroll
        for (int j = 0; j < 8; ++j) {        // sum partials across the 4 quads
            sc[j] += __shfl_xor(sc[j], 16);
            sc[j] += __shfl_xor(sc[j], 32);
        }
        const int diag = l15 & 7;            // row mod 8 (n0 is 16-aligned)
        float mx = -1e30f;
#pragma unroll
        for (int j = 0; j < 8; ++j) if (j != diag) mx = fmaxf(mx, sc[j]);
        float ex[8], sum = 0.f;
#pragma unroll
        for (int j = 0; j < 8; ++j) {
            ex[j] = (j == diag) ? 0.f : __expf(sc[j] - mx);
            sum += ex[j];
        }
        float inv = 1.f / sum;
        if (quad == 0) {                     // one writer per row
            *(float4*)&AT[l15 * 8] =
                make_float4(ex[0] * inv, ex[1] * inv, ex[2] * inv, ex[3] * inv);
            *(float4*)&AT[l15 * 8 + 4] =
                make_float4(ex[4] * inv, ex[5] * inv, ex[6] * inv, ex[7] * inv);
        }
    }

    // ---- prefetch before barrier: phase-B A-frags + half-0 act loads ----
    const int jB  = l15 & 7;
    const int nbh = l15 >> 3;
    bf16x8 WAh[4];
#pragma unroll
    for (int mt = 0; mt < 4; ++mt) {
        int off = ((mt * 16 + l15) * 32 + quad * 8) * 2;
        WAh[mt] = *(const bf16x8*)(ws + OFF_WA_H + off);
    }
    float4 bv0a[4], bv0b[4];
#pragma unroll
    for (int ii = 0; ii < 4; ++ii) {
        int nb = ii * 2 + nbh;
        const float* ap = act + (size_t)(n0 + nb) * 256 + jB * 32 + quad * 8;
        bv0a[ii] = ((const float4*)ap)[0];
        bv0b[ii] = ((const float4*)ap)[1];
    }
    SB();
    __syncthreads();                         // intra-wave: HV/AT visible

    // ---- Phase B half 1 prefetch, then compute half 0 ----
    float4 bv1a[4], bv1b[4];
#pragma unroll
    for (int ii = 0; ii < 4; ++ii) {
        int nb = (4 + ii) * 2 + nbh;
        const float* ap = act + (size_t)(n0 + nb) * 256 + jB * 32 + quad * 8;
        bv1a[ii] = ((const float4*)ap)[0];
        bv1b[ii] = ((const float4*)ap)[1];
    }
    SB();

#pragma unroll
    for (int half = 0; half < 2; ++half) {
#pragma unroll
        for (int ii = 0; ii < 4; ++ii) {
            int nb = (half * 4 + ii) * 2 + nbh;
            bf16x8 Bh = (half == 0) ? cvt8(bv0a[ii], bv0b[ii])
                                    : cvt8(bv1a[ii], bv1b[ii]);
            f32x4 accB[4] = {zv, zv, zv, zv};
#pragma unroll
            for (int mt = 0; mt < 4; ++mt)
                accB[mt] = MFMA(WAh[mt], Bh, accB[mt]);
            int hrow = (nb & 8) + jB;        // h_rep row within wave's 16 rows
            float at = AT[nb * 8 + jB];
#pragma unroll
            for (int mt = 0; mt < 4; ++mt) {
                int d0 = mt * 16 + quad * 4;
                float4 hv4 = *(const float4*)&HV[hrow * 68 + d0];
                float r0 = at * fmaxf(accB[mt][0] + hv4.x, 0.f);
                float r1 = at * fmaxf(accB[mt][1] + hv4.y, 0.f);
                float r2 = at * fmaxf(accB[mt][2] + hv4.z, 0.f);
                float r3 = at * fmaxf(accB[mt][3] + hv4.w, 0.f);
#pragma unroll
                for (int m = 1; m <= 4; m <<= 1) {   // intra-8 xor: DPP, cheap
                    r0 += __shfl_xor(r0, m);
                    r1 += __shfl_xor(r1, m);
                    r2 += __shfl_xor(r2, m);
                    r3 += __shfl_xor(r3, m);
                }
                if (jB == 0)                 // S row nb, d0..d0+3, bf16-packed
                    *(uint2*)&SS[nb * 72 + d0] = make_uint2(pk2(r0, r1), pk2(r2, r3));
            }
        }
        if (half == 0) SB();                 // keep W2 loads below until h0 done
    }

    // ---- W2 fragment loads (4KB shared, L1/L2-hot), batched ----
    float4 wva[4], wvb[4];                   // c = et*2 + kc
#pragma unroll
    for (int c = 0; c < 4; ++c) {
        const float* wp = wv2 + ((c >> 1) * 16 + l15) * 64 + (c & 1) * 32 + quad * 8;
        wva[c] = ((const float4*)wp)[0];
        wvb[c] = ((const float4*)wp)[1];
    }
    SB();
    __syncthreads();                         // intra-wave: SS visible

    // ---- Wv2 via MFMA (hi-only): out[16x32] = S[16x64] . W2^T ----
    {
        bf16x8 Sb[2];
#pragma unroll
        for (int kc = 0; kc < 2; ++kc)
            Sb[kc] = *(const bf16x8*)&SS[l15 * 72 + kc * 32 + quad * 8];
        f32x4 acc2[2] = {zv, zv};
#pragma unroll
        for (int c = 0; c < 4; ++c) {
            bf16x8 Ah = cvt8(wva[c], wvb[c]);
            acc2[c >> 1] = MFMA(Ah, Sb[c & 1], acc2[c >> 1]);
        }
#pragma unroll
        for (int et = 0; et < 2; ++et) {
            int e0 = et * 16 + quad * 4;
            float4 b = *(const float4*)&wv2b[e0];
            f32x4 a = acc2[et];
            *(float4*)&out[(size_t)(n0 + l15) * 32 + e0] =
                make_float4(a[0] + b.x, a[1] + b.y, a[2] + b.z, a[3] + b.w);
        }
    }
}

extern "C" void kernel_launch(void* const* d_in, const int* in_sizes, int n_in,
                              void* d_out, int out_size, void* d_ws, size_t ws_size,
                              hipStream_t stream) {
    const float* o     = (const float*)d_in[0];
    const float* onx   = (const float*)d_in[1];
    const float* h     = (const float*)d_in[2];
    const float* act   = (const float*)d_in[3];
    const float* wq_w  = (const float*)d_in[4];
    const float* wq_b  = (const float*)d_in[5];
    const float* wk_w  = (const float*)d_in[6];
    // d_in[7] = wk_b unused (softmax-invariant, diagonal masked)
    const float* wv1_w = (const float*)d_in[8];
    const float* wv1_b = (const float*)d_in[9];
    const float* wv2_w = (const float*)d_in[10];
    const float* wv2_b = (const float*)d_in[11];
    float* out = (float*)d_out;
    char* ws   = (char*)d_ws;   // needs ~105 KB

    k_setup<<<105, 256, 0, stream>>>(wq_w, wq_b, wk_w, wv1_w, ws);
    fused<<<4096, 64, 0, stream>>>(o, onx, h, act, wv1_b, wv2_w, wv2_b, ws, out);
}

// Round 10
// 235.659 us; speedup vs baseline: 1.0023x; 1.0023x over previous
//
#include <hip/hip_runtime.h>
#include <hip/hip_bf16.h>

// B=8192, A=8, OBS=128, NACT=32, H=256, D=64 ; N = 65536 rows
typedef __attribute__((ext_vector_type(8))) short bf16x8;   // 8 bf16 (4 VGPRs)
typedef __attribute__((ext_vector_type(4))) float f32x4;

#define MFMA(A, B, C) __builtin_amdgcn_mfma_f32_16x16x32_bf16((A), (B), (C), 0, 0, 0)

// ---- ws byte offsets: weights pre-split to bf16 hi/lo planes, [out][k] layout ----
// (lo planes written by setup, unread since round 8: hi-only bf16 verified)
#define OFF_TB    0          // f32 [32]   folded t bias
#define OFF_WT_H  128        // bf16 [32][256]  Mt = SCALE*wk^T*wq
#define OFF_WT_L  16512
#define OFF_WHV_H 32896      // bf16 [64][256]  wv1 h-part
#define OFF_WHV_L 65664
#define OFF_WA_H  98432      // bf16 [64][32]   wv1 action-part
#define OFF_WA_L  102528     // end 106624

// ---- LDS (bytes), total 7168 (round-4 geometry: 16-row single-wave WG) ----
#define SM_HV   0        // f32 [16][68]    4352
#define SM_AT   4352     // f32 [16][8]      512
#define SM_SS   4864     // bf16 [16][72]   2304  (stride 72: rows 16B-aligned)
#define SM_TOT  7168

__device__ __forceinline__ unsigned short f2bf(float v) {   // RNE (setup only)
    unsigned u = __builtin_bit_cast(unsigned, v);
    return (unsigned short)((u + 0x7fffu + ((u >> 16) & 1u)) >> 16);
}
__device__ __forceinline__ float bf2f(unsigned short b) {
    return __builtin_bit_cast(float, ((unsigned)b) << 16);
}
__device__ __forceinline__ ushort2 splitf(float v) {        // (hi, lo residual)
    unsigned short h = f2bf(v);
    unsigned short l = f2bf(v - bf2f(h));
    return make_ushort2(h, l);
}

// __hip_bfloat162 -> u32 reinterpret (bit_cast rejects non-trivially-copyable)
__device__ __forceinline__ unsigned as_u32(__hip_bfloat162 v) {
    unsigned u;
    __builtin_memcpy(&u, &v, sizeof(u));
    return u;
}
__device__ __forceinline__ unsigned pk2(float x, float y) {  // v_cvt_pk_bf16_f32
    return as_u32(__float22bfloat162_rn(make_float2(x, y)));
}
// 8 floats -> bf16x8 (RNE), 4 cvt_pk instrs
__device__ __forceinline__ bf16x8 cvt8(f32x4 a, f32x4 b) {
    uint4 H;
    H.x = pk2(a[0], a[1]);
    H.y = pk2(a[2], a[3]);
    H.z = pk2(b[0], b[1]);
    H.w = pk2(b[2], b[3]);
    return __builtin_bit_cast(bf16x8, H);
}

// ---- inline-asm memory pipeline: issue order pinned by asm volatile, ----
// ---- results FORCED live in VGPRs from issue to use (rounds 8/9 showed ----
// ---- the compiler sinks C++ loads to uses -> ~60 serialized round trips) ----
__device__ __forceinline__ f32x4 gld(const float* p) {
    f32x4 r;
    asm volatile("global_load_dwordx4 %0, %1, off" : "=v"(r) : "v"(p));
    return r;
}
__device__ __forceinline__ f32x4 gldo16(const float* p) {   // p + 4 floats
    f32x4 r;
    asm volatile("global_load_dwordx4 %0, %1, off offset:16" : "=v"(r) : "v"(p));
    return r;
}
__device__ __forceinline__ bf16x8 gldw(const void* p) {
    bf16x8 r;
    asm volatile("global_load_dwordx4 %0, %1, off" : "=v"(r) : "v"(p));
    return r;
}
// drain + fence (sched_barrier keeps consumers below the wait — guide rule #18)
__device__ __forceinline__ void vmwait() {
    asm volatile("s_waitcnt vmcnt(0)" ::: "memory");
    __builtin_amdgcn_sched_barrier(0);
}

// ---------------------------------------------------------------------------
// setup: fold Mt = SCALE*wk^T*wq (+bias), split weights into bf16 planes in
// fragment-native [out][k] layout. wk_b dropped (softmax-invariant, diagonal
// masked — verified round 1).
// ---------------------------------------------------------------------------
__global__ __launch_bounds__(256) void k_setup(const float* __restrict__ wq_w,
                                               const float* __restrict__ wq_b,
                                               const float* __restrict__ wk_w,
                                               const float* __restrict__ wv1,
                                               char* __restrict__ ws) {
    int gid = blockIdx.x * 256 + threadIdx.x;
    if (gid < 8192) {                              // Mt[k][c]
        int k = gid >> 8, c = gid & 255;
        float acc = 0.f;
#pragma unroll 8
        for (int d = 0; d < 64; ++d) acc = fmaf(wk_w[d * 32 + k], wq_w[d * 256 + c], acc);
        ushort2 s = splitf(0.125f * acc);
        ((unsigned short*)(ws + OFF_WT_H))[gid] = s.x;
        ((unsigned short*)(ws + OFF_WT_L))[gid] = s.y;
    } else if (gid < 24576) {                      // wv1 h-part [d][c]
        int i = gid - 8192;
        ushort2 s = splitf(wv1[(i >> 8) * 288 + (i & 255)]);
        ((unsigned short*)(ws + OFF_WHV_H))[i] = s.x;
        ((unsigned short*)(ws + OFF_WHV_L))[i] = s.y;
    } else if (gid < 26624) {                      // wv1 action-part [d][k]
        int i = gid - 24576;
        ushort2 s = splitf(wv1[(i >> 5) * 288 + 256 + (i & 31)]);
        ((unsigned short*)(ws + OFF_WA_H))[i] = s.x;
        ((unsigned short*)(ws + OFF_WA_L))[i] = s.y;
    } else if (gid < 26656) {                      // tb
        int k = gid - 26624;
        float b = 0.f;
#pragma unroll 8
        for (int d = 0; d < 64; ++d) b = fmaf(wk_w[d * 32 + k], wq_b[d], b);
        ((float*)(ws + OFF_TB))[k] = 0.125f * b;
    }
}

// ---------------------------------------------------------------------------
// Fused, block = ONE wave = 16 rows (2 batches). Round 10: round-8 math
// (hi-only bf16) + asm-forced load batching. 12 vmcnt(0) waits/wave instead
// of ~60 serialized load round-trips (round-9 Little's law: 60 us/wave).
// ---------------------------------------------------------------------------
__global__ __launch_bounds__(64, 4) void fused(
    const float* __restrict__ o, const float* __restrict__ onx,
    const float* __restrict__ h, const float* __restrict__ act,
    const float* __restrict__ wv1b, const float* __restrict__ wv2,
    const float* __restrict__ wv2b, const char* __restrict__ ws,
    float* __restrict__ out)
{
    __shared__ __align__(16) char sm[SM_TOT];
    float* HV = (float*)(sm + SM_HV);               // [16][68]
    float* AT = (float*)(sm + SM_AT);               // [16][8]
    unsigned short* SS = (unsigned short*)(sm + SM_SS);  // [16][72]

    const int lane = threadIdx.x;          // 0..63
    const int l15  = lane & 15;
    const int quad = lane >> 4;
    const int n0   = blockIdx.x * 16;
    const int myrow = n0 + l15;            // phase-A fragment row of this lane

    const f32x4 zv = {0.f, 0.f, 0.f, 0.f};
    f32x4 acc_hv[4] = {zv, zv, zv, zv};
    f32x4 acc_t[2]  = {zv, zv};

    bf16x8 Bx[8];                          // act chunks as bf16 (32 VGPR)

    // ---- Phase A-x: 16 loads in flight -> 1 wait; weights 8/batch -> 1 wait/mt
    {
        f32x4 xa[8], xb[8];
#pragma unroll
        for (int ch = 0; ch < 8; ++ch) {
            const float* src = (ch < 4)
                ? o   + (size_t)myrow * 128 + ch * 32 + quad * 8
                : onx + (size_t)myrow * 128 + (ch - 4) * 32 + quad * 8;
            xa[ch] = gld(src);
            xb[ch] = gldo16(src);
        }
        vmwait();
#pragma unroll
        for (int ch = 0; ch < 8; ++ch) Bx[ch] = cvt8(xa[ch], xb[ch]);
    }
#pragma unroll
    for (int mt = 0; mt < 2; ++mt) {
        bf16x8 wf[8];
#pragma unroll
        for (int ch = 0; ch < 8; ++ch)
            wf[ch] = gldw(ws + OFF_WT_H + (((mt * 16 + l15) * 256) + ch * 32 + quad * 8) * 2);
        vmwait();
#pragma unroll
        for (int ch = 0; ch < 8; ++ch) acc_t[mt] = MFMA(wf[ch], Bx[ch], acc_t[mt]);
    }

    // ---- Phase A-h: same structure, 4 mt ----
    {
        f32x4 xa[8], xb[8];
#pragma unroll
        for (int ch = 0; ch < 8; ++ch) {
            const float* src = h + (size_t)myrow * 256 + ch * 32 + quad * 8;
            xa[ch] = gld(src);
            xb[ch] = gldo16(src);
        }
        vmwait();
#pragma unroll
        for (int ch = 0; ch < 8; ++ch) Bx[ch] = cvt8(xa[ch], xb[ch]);
    }
#pragma unroll
    for (int mt = 0; mt < 4; ++mt) {
        bf16x8 wf[8];
#pragma unroll
        for (int ch = 0; ch < 8; ++ch)
            wf[ch] = gldw(ws + OFF_WHV_H + (((mt * 16 + l15) * 256) + ch * 32 + quad * 8) * 2);
        vmwait();
#pragma unroll
        for (int ch = 0; ch < 8; ++ch) acc_hv[mt] = MFMA(wf[ch], Bx[ch], acc_hv[mt]);
    }

    // ---- scores batch 0: bias(4) + tb(2) + act j0-3 (8) = 14 loads, 1 wait ----
    const float* arow = act + (size_t)myrow * 256;
    const float* tbp  = (const float*)(ws + OFF_TB);
    f32x4 b4[4], tb0, tb1, av0[8], av1[8];
#pragma unroll
    for (int mt = 0; mt < 4; ++mt) b4[mt] = gld(&wv1b[mt * 16 + quad * 4]);
    tb0 = gld(tbp + quad * 4);
    tb1 = gld(tbp + 16 + quad * 4);
#pragma unroll
    for (int j = 0; j < 4; ++j) {
        av0[j] = gld(arow + j * 32 + quad * 4);
        av1[j] = gld(arow + j * 32 + 16 + quad * 4);
    }
    vmwait();

    // ---- epilogue A: HV to LDS (col=l15 -> row n, row=quad*4+reg -> d) ----
#pragma unroll
    for (int mt = 0; mt < 4; ++mt) {
        int d0 = mt * 16 + quad * 4;
        f32x4 a = acc_hv[mt];
        *(float4*)&HV[l15 * 68 + d0] =
            make_float4(a[0] + b4[mt][0], a[1] + b4[mt][1],
                        a[2] + b4[mt][2], a[3] + b4[mt][3]);
    }

    float sc[8];
    {
        float t8[8];
#pragma unroll
        for (int r = 0; r < 4; ++r) {
            t8[r]     = acc_t[0][r] + tb0[r];
            t8[4 + r] = acc_t[1][r] + tb1[r];
        }
        // issue scores batch 1 (j4-7) before computing sc[0..3]
#pragma unroll
        for (int j = 4; j < 8; ++j) {
            av0[j] = gld(arow + j * 32 + quad * 4);
            av1[j] = gld(arow + j * 32 + 16 + quad * 4);
        }
#pragma unroll
        for (int j = 0; j < 4; ++j) {
            float s = 0.f;
            s = fmaf(t8[0], av0[j][0], s); s = fmaf(t8[1], av0[j][1], s);
            s = fmaf(t8[2], av0[j][2], s); s = fmaf(t8[3], av0[j][3], s);
            s = fmaf(t8[4], av1[j][0], s); s = fmaf(t8[5], av1[j][1], s);
            s = fmaf(t8[6], av1[j][2], s); s = fmaf(t8[7], av1[j][3], s);
            sc[j] = s;
        }
        vmwait();
#pragma unroll
        for (int j = 4; j < 8; ++j) {
            float s = 0.f;
            s = fmaf(t8[0], av0[j][0], s); s = fmaf(t8[1], av0[j][1], s);
            s = fmaf(t8[2], av0[j][2], s); s = fmaf(t8[3], av0[j][3], s);
            s = fmaf(t8[4], av1[j][0], s); s = fmaf(t8[5], av1[j][1], s);
            s = fmaf(t8[6], av1[j][2], s); s = fmaf(t8[7], av1[j][3], s);
            sc[j] = s;
        }
    }

    // ---- softmax (in-register, per-lane row) ----
    {
#pragma unroll
        for (int j = 0; j < 8; ++j) {        // sum partials across the 4 quads
            sc[j] += __shfl_xor(sc[j], 16);
            sc[j] += __shfl_xor(sc[j], 32);
        }
        const int diag = l15 & 7;            // row mod 8 (n0 is 16-aligned)
        float mx = -1e30f;
#pragma unroll
        for (int j = 0; j < 8; ++j) if (j != diag) mx = fmaxf(mx, sc[j]);
        float ex[8], sum = 0.f;
#pragma unroll
        for (int j = 0; j < 8; ++j) {
            ex[j] = (j == diag) ? 0.f : __expf(sc[j] - mx);
            sum += ex[j];
        }
        float inv = 1.f / sum;
        if (quad == 0) {                     // one writer per row
            *(float4*)&AT[l15 * 8] =
                make_float4(ex[0] * inv, ex[1] * inv, ex[2] * inv, ex[3] * inv);
            *(float4*)&AT[l15 * 8 + 4] =
                make_float4(ex[4] * inv, ex[5] * inv, ex[6] * inv, ex[7] * inv);
        }
    }

    // ---- Phase B: WA(4) + half0(8) in flight across the barrier, +half1(8),
    // ---- single wait covers all 20 loads ----
    const int jB  = l15 & 7;
    const int nbh = l15 >> 3;
    bf16x8 WAh[4];
#pragma unroll
    for (int mt = 0; mt < 4; ++mt)
        WAh[mt] = gldw(ws + OFF_WA_H + ((mt * 16 + l15) * 32 + quad * 8) * 2);
    f32x4 bv0a[4], bv0b[4];
#pragma unroll
    for (int ii = 0; ii < 4; ++ii) {
        int nb = ii * 2 + nbh;
        const float* ap = act + (size_t)(n0 + nb) * 256 + jB * 32 + quad * 8;
        bv0a[ii] = gld(ap);
        bv0b[ii] = gldo16(ap);
    }
    __syncthreads();                         // intra-wave: HV/AT visible
    f32x4 bv1a[4], bv1b[4];
#pragma unroll
    for (int ii = 0; ii < 4; ++ii) {
        int nb = (4 + ii) * 2 + nbh;
        const float* ap = act + (size_t)(n0 + nb) * 256 + jB * 32 + quad * 8;
        bv1a[ii] = gld(ap);
        bv1b[ii] = gldo16(ap);
    }
    vmwait();

#pragma unroll
    for (int half = 0; half < 2; ++half) {
#pragma unroll
        for (int ii = 0; ii < 4; ++ii) {
            int nb = (half * 4 + ii) * 2 + nbh;
            bf16x8 Bh = (half == 0) ? cvt8(bv0a[ii], bv0b[ii])
                                    : cvt8(bv1a[ii], bv1b[ii]);
            f32x4 accB[4] = {zv, zv, zv, zv};
#pragma unroll
            for (int mt = 0; mt < 4; ++mt)
                accB[mt] = MFMA(WAh[mt], Bh, accB[mt]);
            int hrow = (nb & 8) + jB;        // h_rep row within wave's 16 rows
            float at = AT[nb * 8 + jB];
#pragma unroll
            for (int mt = 0; mt < 4; ++mt) {
                int d0 = mt * 16 + quad * 4;
                float4 hv4 = *(const float4*)&HV[hrow * 68 + d0];
                float r0 = at * fmaxf(accB[mt][0] + hv4.x, 0.f);
                float r1 = at * fmaxf(accB[mt][1] + hv4.y, 0.f);
                float r2 = at * fmaxf(accB[mt][2] + hv4.z, 0.f);
                float r3 = at * fmaxf(accB[mt][3] + hv4.w, 0.f);
#pragma unroll
                for (int m = 1; m <= 4; m <<= 1) {
                    r0 += __shfl_xor(r0, m);
                    r1 += __shfl_xor(r1, m);
                    r2 += __shfl_xor(r2, m);
                    r3 += __shfl_xor(r3, m);
                }
                if (jB == 0)                 // S row nb, d0..d0+3, bf16-packed
                    *(uint2*)&SS[nb * 72 + d0] = make_uint2(pk2(r0, r1), pk2(r2, r3));
            }
        }
    }

    // ---- W2 loads (8) in flight across the barrier, 1 wait ----
    f32x4 wva[4], wvb[4];                    // c = et*2 + kc
#pragma unroll
    for (int c = 0; c < 4; ++c) {
        const float* wp = wv2 + ((c >> 1) * 16 + l15) * 64 + (c & 1) * 32 + quad * 8;
        wva[c] = gld(wp);
        wvb[c] = gldo16(wp);
    }
    __syncthreads();                         // intra-wave: SS visible

    // ---- Wv2 via MFMA (hi-only): out[16x32] = S[16x64] . W2^T ----
    {
        bf16x8 Sb[2];
#pragma unroll
        for (int kc = 0; kc < 2; ++kc)
            Sb[kc] = *(const bf16x8*)&SS[l15 * 72 + kc * 32 + quad * 8];
        vmwait();
        f32x4 acc2[2] = {zv, zv};
#pragma unroll
        for (int c = 0; c < 4; ++c) {
            bf16x8 Ah = cvt8(wva[c], wvb[c]);
            acc2[c >> 1] = MFMA(Ah, Sb[c & 1], acc2[c >> 1]);
        }
#pragma unroll
        for (int et = 0; et < 2; ++et) {
            int e0 = et * 16 + quad * 4;
            float4 b = *(const float4*)&wv2b[e0];
            f32x4 a = acc2[et];
            *(float4*)&out[(size_t)(n0 + l15) * 32 + e0] =
                make_float4(a[0] + b.x, a[1] + b.y, a[2] + b.z, a[3] + b.w);
        }
    }
}

extern "C" void kernel_launch(void* const* d_in, const int* in_sizes, int n_in,
                              void* d_out, int out_size, void* d_ws, size_t ws_size,
                              hipStream_t stream) {
    const float* o     = (const float*)d_in[0];
    const float* onx   = (const float*)d_in[1];
    const float* h     = (const float*)d_in[2];
    const float* act   = (const float*)d_in[3];
    const float* wq_w  = (const float*)d_in[4];
    const float* wq_b  = (const float*)d_in[5];
    const float* wk_w  = (const float*)d_in[6];
    // d_in[7] = wk_b unused (softmax-invariant, diagonal masked)
    const float* wv1_w = (const float*)d_in[8];
    const float* wv1_b = (const float*)d_in[9];
    const float* wv2_w = (const float*)d_in[10];
    const float* wv2_b = (const float*)d_in[11];
    float* out = (float*)d_out;
    char* ws   = (char*)d_ws;   // needs ~105 KB

    k_setup<<<105, 256, 0, stream>>>(wq_w, wq_b, wk_w, wv1_w, ws);
    fused<<<4096, 64, 0, stream>>>(o, onx, h, act, wv1_b, wv2_w, wv2_b, ws, out);
}